// Round 6
// baseline (304.497 us; speedup 1.0000x reference)
//
#include <hip/hip_runtime.h>

typedef __attribute__((ext_vector_type(8))) short short8;
typedef __attribute__((ext_vector_type(4))) short short4v;
typedef __attribute__((ext_vector_type(4))) float floatx4;

__device__ __forceinline__ unsigned short f2bf(float f) {
    unsigned int u = __float_as_uint(f);
    u += 0x7FFFu + ((u >> 16) & 1u);   // round-to-nearest-even
    return (unsigned short)(u >> 16);
}
__device__ __forceinline__ float bf2f(unsigned short s) {
    return __uint_as_float(((unsigned int)s) << 16);
}
__device__ __forceinline__ float sigmoidf(float x) {
    return 1.f / (1.f + __expf(-x));
}

// Wf|Wa fp32 [256,512] -> bf16, MFMA A-operand fragment order.
// short8 index = (g*16 + ks)*64 + lane; lane slot lk*16+l15 holds
// W[d = g*16+l15][k = ks*32+lk*8 .. +8].  g<16 -> Wf, g>=16 -> Wa.
__global__ __launch_bounds__(256)
void convert_w_kernel(const float* __restrict__ Wf,
                      const float* __restrict__ Wa,
                      short* __restrict__ wswz)
{
    int id = blockIdx.x * 256 + threadIdx.x;       // 32768 total
    int slot = id & 63;
    int ks   = (id >> 6) & 15;
    int g    = id >> 10;
    int l15  = slot & 15, lk = slot >> 4;
    const float* base = (g < 16) ? (Wf + (long)(g * 16 + l15) * 512)
                                 : (Wa + (long)((g - 16) * 16 + l15) * 512);
    const float* src = base + ks * 32 + lk * 8;
    floatx4 w0 = *(const floatx4*)src;
    floatx4 w1 = *(const floatx4*)(src + 4);
    short8 o;
    o[0] = (short)f2bf(w0[0]); o[1] = (short)f2bf(w0[1]);
    o[2] = (short)f2bf(w0[2]); o[3] = (short)f2bf(w0[3]);
    o[4] = (short)f2bf(w1[0]); o[5] = (short)f2bf(w1[1]);
    o[6] = (short)f2bf(w1[2]); o[7] = (short)f2bf(w1[3]);
    *(short8*)(wswz + (long)id * 8) = o;
}

// Zero the flags array (own kernel: rocclr fillBuffer showed ~157us anomalies).
__global__ __launch_bounds__(256)
void zero_flags_kernel(unsigned int* __restrict__ flags)   // 256 KB = 65536 u32
{
    flags[blockIdx.x * 256 + threadIdx.x] = 0u;
}

// Mark updated rows.
__global__ __launch_bounds__(256)
void mark_kernel(const int* __restrict__ ei, const int* __restrict__ ti,
                 unsigned char* __restrict__ flags, int n)
{
    int i = blockIdx.x * 256 + threadIdx.x;
    if (i < n) flags[64 * ei[i] + ti[i]] = 1;
}

// Copy rows NOT updated (one wave per row; wave-uniform flag branch).
__global__ __launch_bounds__(256)
void copy_rest_kernel(const float* __restrict__ flat,
                      const unsigned char* __restrict__ flags,
                      float* __restrict__ out, int nrows)
{
    const int lane = threadIdx.x & 63;
    const int w0   = (blockIdx.x * 256 + threadIdx.x) >> 6;
    const int nw   = (gridDim.x * 256) >> 6;
    for (int row = w0; row < nrows; row += nw) {
        if (flags[row]) continue;
        const floatx4* s = (const floatx4*)(flat + (long)row * 256);
        floatx4*       o = (floatx4*)(out + (long)row * 256);
        o[lane] = s[lane];
    }
}

// Pipelined fused gather + bf16 GEMM + gates + combine + scatter.
// Grid 256 blocks x TPB tiles; block = 1024 threads (16 waves), tile = 64 occ
// rows. Single 64KB LDS buffer, XOR-swizzled (chunk ^= row&7, 16B chunks) --
// write / fragment-read / epilogue-read patterns are all bank-balanced.
// Per-tile: convert regs->bf16, barrier, ds_write, barrier, ISSUE NEXT TILE'S
// GATHER LOADS (to VGPRs), then MFMA+epilogue -- loads fly under compute, so
// gather latency is hidden (T14 async-stage split with plain barriers).
// Wave w owns d in [16w,16w+16) for both gates (acc[4][2]).
__global__ __launch_bounds__(1024, 4)
void gate_pipe_kernel(const float* __restrict__ flat,   // [262144,256]
                      const float* __restrict__ syms,   // [20000,256]
                      const float* __restrict__ bfb,
                      const float* __restrict__ bab,
                      const int* __restrict__ ei,
                      const int* __restrict__ ti,
                      const int* __restrict__ si,
                      const short* __restrict__ wswz,
                      float* __restrict__ out,
                      int ntiles, int tpb)
{
    __shared__ __align__(16) short A_lds[64 * 512];   // 64 KB

    const int tid  = threadIdx.x;
    const int srow = tid >> 4;     // 0..63: staged row
    const int se   = tid & 15;     // 16 threads per row
    const int sw   = srow & 7;

    const int lane = tid & 63;
    const int w    = tid >> 6;     // wave 0..15
    const int l15  = lane & 15;
    const int lk   = lane >> 4;

    const int tfirst = blockIdx.x * tpb;

    floatx4 v[8];   // in-flight gathered tile data (32 VGPR)
    auto issue = [&](int tile) {
        const int occ = tile * 64 + srow;
        const long row = 64 * ei[occ] + ti[occ];
        const long sym = si[occ];
        const float* pr = flat + row * 256;
        const float* ur = syms + sym * 256;
        v[0] = *(const floatx4*)(pr + se * 8);
        v[1] = *(const floatx4*)(pr + se * 8 + 4);
        v[2] = *(const floatx4*)(pr + (se + 16) * 8);
        v[3] = *(const floatx4*)(pr + (se + 16) * 8 + 4);
        v[4] = *(const floatx4*)(ur + se * 8);
        v[5] = *(const floatx4*)(ur + se * 8 + 4);
        v[6] = *(const floatx4*)(ur + (se + 16) * 8);
        v[7] = *(const floatx4*)(ur + (se + 16) * 8 + 4);
    };

    if (tfirst < ntiles) issue(tfirst);

    const int d0 = w * 16 + lk * 4;
    const floatx4 bfv = *(const floatx4*)(bfb + d0);
    const floatx4 bav = *(const floatx4*)(bab + d0);
    const short8* wsv = (const short8*)wswz;

    for (int t = 0; t < tpb; ++t) {
        const int tile = tfirst + t;
        if (tile >= ntiles) break;

        // ---- convert current tile's regs -> bf16 (register-only) ----
        short8 s8[4];
        #pragma unroll
        for (int h = 0; h < 4; ++h) {
            floatx4 a = v[h * 2], b = v[h * 2 + 1];
            short8 o;
            o[0] = (short)f2bf(a[0]); o[1] = (short)f2bf(a[1]);
            o[2] = (short)f2bf(a[2]); o[3] = (short)f2bf(a[3]);
            o[4] = (short)f2bf(b[0]); o[5] = (short)f2bf(b[1]);
            o[6] = (short)f2bf(b[2]); o[7] = (short)f2bf(b[3]);
            s8[h] = o;
        }

        __syncthreads();   // all waves done reading LDS (previous tile)

        // ---- ds_write: chunk = se + h-offset, swizzled by row ----
        #pragma unroll
        for (int h = 0; h < 4; ++h) {
            const int chunk = (se + ((h & 1) << 4) + ((h >> 1) << 5)) ^ sw;
            *(short8*)&A_lds[srow * 512 + chunk * 8] = s8[h];
        }

        __syncthreads();   // LDS tile ready

        // ---- prefetch next tile (lands during compute below) ----
        if (t + 1 < tpb && tile + 1 < ntiles) issue(tile + 1);

        // ---- MFMA: Z^T, A=weights (global/L2), B=rows (LDS) ----
        floatx4 acc[4][2];
        #pragma unroll
        for (int mi = 0; mi < 4; ++mi) {
            acc[mi][0] = (floatx4){0.f, 0.f, 0.f, 0.f};
            acc[mi][1] = (floatx4){0.f, 0.f, 0.f, 0.f};
        }

        #pragma unroll
        for (int ks = 0; ks < 16; ++ks) {
            short8 cb[4];
            #pragma unroll
            for (int mi = 0; mi < 4; ++mi) {
                const int m  = mi * 16 + l15;
                const int ch = (ks * 4 + lk) ^ (m & 7);
                cb[mi] = *(const short8*)&A_lds[m * 512 + ch * 8];
            }
            const short8 wff = wsv[(w * 16 + ks) * 64 + lane];          // forget
            #pragma unroll
            for (int mi = 0; mi < 4; ++mi)
                acc[mi][0] = __builtin_amdgcn_mfma_f32_16x16x32_bf16(
                    wff, cb[mi], acc[mi][0], 0, 0, 0);
            const short8 wfa = wsv[((16 + w) * 16 + ks) * 64 + lane];   // add
            #pragma unroll
            for (int mi = 0; mi < 4; ++mi)
                acc[mi][1] = __builtin_amdgcn_mfma_f32_16x16x32_bf16(
                    wfa, cb[mi], acc[mi][1], 0, 0, 0);
        }

        // ---- epilogue: lane owns m = mi*16+l15, d = d0..d0+3 ----
        #pragma unroll
        for (int mi = 0; mi < 4; ++mi) {
            const int m   = mi * 16 + l15;
            const int occ = tile * 64 + m;
            const long row = 64 * ei[occ] + ti[occ];   // L1-hot
            const int cp = (d0 >> 3) ^ (m & 7);
            const int cu = (32 + (d0 >> 3)) ^ (m & 7);
            const int sub = d0 & 7;
            short4v pv = *(const short4v*)&A_lds[m * 512 + cp * 8 + sub];
            short4v uv = *(const short4v*)&A_lds[m * 512 + cu * 8 + sub];
            floatx4 res;
            #pragma unroll
            for (int j = 0; j < 4; ++j) {
                float fg = sigmoidf(acc[mi][0][j] + bfv[j]);
                float ag = sigmoidf(acc[mi][1][j] + bav[j]);
                res[j] = fg * bf2f((unsigned short)pv[j])
                       + ag * bf2f((unsigned short)uv[j]);
            }
            *(floatx4*)(out + row * 256 + d0) = res;
        }
    }
}

extern "C" void kernel_launch(void* const* d_in, const int* in_sizes, int n_in,
                              void* d_out, int out_size, void* d_ws, size_t ws_size,
                              hipStream_t stream) {
    const float* flat = (const float*)d_in[0];
    const float* syms = (const float*)d_in[1];
    const float* Wf   = (const float*)d_in[2];
    const float* bf   = (const float*)d_in[3];
    const float* Wa   = (const float*)d_in[4];
    const float* ba   = (const float*)d_in[5];
    const int* ei     = (const int*)d_in[6];
    const int* ti     = (const int*)d_in[7];
    const int* si     = (const int*)d_in[8];
    float* out        = (float*)d_out;

    short* wswz          = (short*)d_ws;                        // 512 KB
    unsigned char* flags = (unsigned char*)d_ws + 512 * 1024;   // 256 KB

    const int n_occ = in_sizes[6];        // 131072
    const int nrows = out_size / 256;     // 262144

    zero_flags_kernel<<<nrows / 1024, 256, 0, stream>>>((unsigned int*)flags);
    mark_kernel<<<(n_occ + 255) / 256, 256, 0, stream>>>(ei, ti, flags, n_occ);
    convert_w_kernel<<<128, 256, 0, stream>>>(Wf, Wa, wswz);

    const int ntiles = n_occ / 64;                 // 2048
    const int nblk   = 256;
    const int tpb    = (ntiles + nblk - 1) / nblk; // 8
    gate_pipe_kernel<<<nblk, 1024, 0, stream>>>(flat, syms, bf, ba,
                                                ei, ti, si, wswz, out,
                                                ntiles, tpb);

    copy_rest_kernel<<<2048, 256, 0, stream>>>(flat, flags, out, nrows);
}

// Round 7
// 297.761 us; speedup vs baseline: 1.0226x; 1.0226x over previous
//
#include <hip/hip_runtime.h>

typedef __attribute__((ext_vector_type(8))) short short8;
typedef __attribute__((ext_vector_type(4))) short short4v;
typedef __attribute__((ext_vector_type(4))) float floatx4;

__device__ __forceinline__ unsigned short f2bf(float f) {
    unsigned int u = __float_as_uint(f);
    u += 0x7FFFu + ((u >> 16) & 1u);   // round-to-nearest-even
    return (unsigned short)(u >> 16);
}
__device__ __forceinline__ float bf2f(unsigned short s) {
    return __uint_as_float(((unsigned int)s) << 16);
}
__device__ __forceinline__ float sigmoidf(float x) {
    return 1.f / (1.f + __expf(-x));
}

// Wf|Wa fp32 [256,512] -> bf16, MFMA A-operand fragment order.
// short8 index = (g*16 + ks)*64 + lane; lane slot lk*16+l15 holds
// W[d = g*16+l15][k = ks*32+lk*8 .. +8].  g<16 -> Wf, g>=16 -> Wa.
__global__ __launch_bounds__(256)
void convert_w_kernel(const float* __restrict__ Wf,
                      const float* __restrict__ Wa,
                      short* __restrict__ wswz)
{
    int id = blockIdx.x * 256 + threadIdx.x;       // 32768 total
    int slot = id & 63;
    int ks   = (id >> 6) & 15;
    int g    = id >> 10;
    int l15  = slot & 15, lk = slot >> 4;
    const float* base = (g < 16) ? (Wf + (long)(g * 16 + l15) * 512)
                                 : (Wa + (long)((g - 16) * 16 + l15) * 512);
    const float* src = base + ks * 32 + lk * 8;
    floatx4 w0 = *(const floatx4*)src;
    floatx4 w1 = *(const floatx4*)(src + 4);
    short8 o;
    o[0] = (short)f2bf(w0[0]); o[1] = (short)f2bf(w0[1]);
    o[2] = (short)f2bf(w0[2]); o[3] = (short)f2bf(w0[3]);
    o[4] = (short)f2bf(w1[0]); o[5] = (short)f2bf(w1[1]);
    o[6] = (short)f2bf(w1[2]); o[7] = (short)f2bf(w1[3]);
    *(short8*)(wswz + (long)id * 8) = o;
}

__global__ __launch_bounds__(256)
void zero_flags_kernel(unsigned int* __restrict__ flags)   // 256 KB
{
    flags[blockIdx.x * 256 + threadIdx.x] = 0u;
}

__global__ __launch_bounds__(256)
void mark_kernel(const int* __restrict__ ei, const int* __restrict__ ti,
                 unsigned char* __restrict__ flags, int n)
{
    int i = blockIdx.x * 256 + threadIdx.x;
    if (i < n) flags[64 * ei[i] + ti[i]] = 1;
}

// Fused main kernel: gate-GEMM blocks and copy blocks co-scheduled in one
// grid (Bresenham 2:1 interleave) so the BW-bound copy stream soaks HBM
// while gate blocks are in latency/compute phases.
//
// Gate block (512 thr, 8 waves, 64 occ rows, 64KB LDS):
//   stage: wave w stages rows w*8..w*8+7; ALL 16 gather loads issued before
//          any convert (16-deep VMEM) -> BW-bound gather. ds_write_b128:
//          one full 1KB row per wave, chunk ^= row&7 (pure permutation,
//          conflict-free).
//   compute: two row-halves sequentially (acc[2][4] = 32 AGPR, frees arch
//          VGPRs for the deep stage + weight prefetch). Weights from L2 in
//          A-operand fragment order, prefetched 1 ks ahead.
//   epilogue: per-half; gates+combine from LDS bf16; dwordx4 scatter.
__global__ __launch_bounds__(512, 4)
void main_kernel(const float* __restrict__ flat,   // [262144,256]
                 const float* __restrict__ syms,   // [20000,256]
                 const float* __restrict__ bfb,
                 const float* __restrict__ bab,
                 const int* __restrict__ ei,
                 const int* __restrict__ ti,
                 const int* __restrict__ si,
                 const short* __restrict__ wswz,
                 const unsigned char* __restrict__ flags,
                 float* __restrict__ out,
                 int ntiles, int ncopy)
{
    __shared__ __align__(16) short A_lds[64 * 512];   // 64 KB

    const int bid   = blockIdx.x;
    const int total = ntiles + ncopy;
    const int tid   = threadIdx.x;
    const int lane  = tid & 63;
    const int w     = tid >> 6;    // wave 0..7

    // Bresenham split: copy blocks evenly interleaved among gate blocks.
    const int c_before = (int)(((long)bid * ncopy) / total);
    const bool is_copy = (int)(((long)(bid + 1) * ncopy) / total) > c_before;

    if (is_copy) {
        // ---- copy path: 256 rows, one row per wave per iter ----
        const int r0 = c_before * 256;
        for (int it = 0; it < 32; ++it) {
            const int row = r0 + it * 8 + w;
            if (flags[row]) continue;
            const floatx4* s = (const floatx4*)(flat + (long)row * 256);
            floatx4*       o = (floatx4*)(out + (long)row * 256);
            o[lane] = s[lane];
        }
        return;
    }

    const int tile = bid - c_before;
    const int occ0 = tile * 64;

    // ---- stage: wave w stages rows w*8 .. w*8+7, lane = 16B chunk ----
    {
        int rowi[8], symi[8];
        #pragma unroll
        for (int i = 0; i < 8; ++i) {
            const int occ = occ0 + w * 8 + i;
            rowi[i] = 64 * ei[occ] + ti[occ];
            symi[i] = si[occ];
        }
        floatx4 va[8], vb[8];
        #pragma unroll
        for (int i = 0; i < 8; ++i) {
            const float* base = (lane < 32)
                ? (flat + (long)rowi[i] * 256 + lane * 8)
                : (syms + (long)symi[i] * 256 + (lane - 32) * 8);
            va[i] = *(const floatx4*)base;
            vb[i] = *(const floatx4*)(base + 4);
        }
        #pragma unroll
        for (int i = 0; i < 8; ++i) {
            short8 o;
            o[0] = (short)f2bf(va[i][0]); o[1] = (short)f2bf(va[i][1]);
            o[2] = (short)f2bf(va[i][2]); o[3] = (short)f2bf(va[i][3]);
            o[4] = (short)f2bf(vb[i][0]); o[5] = (short)f2bf(vb[i][1]);
            o[6] = (short)f2bf(vb[i][2]); o[7] = (short)f2bf(vb[i][3]);
            const int r = w * 8 + i;
            *(short8*)&A_lds[r * 512 + ((lane ^ (r & 7)) << 3)] = o;
        }
    }
    __syncthreads();

    const int l15 = lane & 15;
    const int lk  = lane >> 4;
    const short8* wsv = (const short8*)wswz;

    // biases for this wave's d-slice (d0 = w*32 + c*16 + lk*4)
    floatx4 bfv[2], bav[2];
    #pragma unroll
    for (int c = 0; c < 2; ++c) {
        const int d0 = w * 32 + c * 16 + lk * 4;
        bfv[c] = *(const floatx4*)(bfb + d0);
        bav[c] = *(const floatx4*)(bab + d0);
    }

    #pragma unroll
    for (int h = 0; h < 2; ++h) {
        floatx4 acc[2][4];   // [mi][c: 0,1=forget, 2,3=add] -> 32 AGPR
        #pragma unroll
        for (int mi = 0; mi < 2; ++mi)
            #pragma unroll
            for (int c = 0; c < 4; ++c)
                acc[mi][c] = (floatx4){0.f, 0.f, 0.f, 0.f};

        // prefetch ks=0 weights
        short8 wfc[4];
        #pragma unroll
        for (int c = 0; c < 4; ++c) {
            const int g = (c < 2) ? (w * 2 + c) : (16 + w * 2 + (c - 2));
            wfc[c] = wsv[(g * 16 + 0) * 64 + lane];
        }

        #pragma unroll
        for (int ks = 0; ks < 16; ++ks) {
            short8 cb[2];
            #pragma unroll
            for (int mi = 0; mi < 2; ++mi) {
                const int m  = (h * 2 + mi) * 16 + l15;
                const int ch = (ks * 4 + lk) ^ (m & 7);
                cb[mi] = *(const short8*)&A_lds[m * 512 + (ch << 3)];
            }
            short8 wfn[4];
            if (ks < 15) {
                #pragma unroll
                for (int c = 0; c < 4; ++c) {
                    const int g = (c < 2) ? (w * 2 + c) : (16 + w * 2 + (c - 2));
                    wfn[c] = wsv[(g * 16 + ks + 1) * 64 + lane];
                }
            }
            #pragma unroll
            for (int c = 0; c < 4; ++c)
                #pragma unroll
                for (int mi = 0; mi < 2; ++mi)
                    acc[mi][c] = __builtin_amdgcn_mfma_f32_16x16x32_bf16(
                        wfc[c], cb[mi], acc[mi][c], 0, 0, 0);
            if (ks < 15) {
                #pragma unroll
                for (int c = 0; c < 4; ++c) wfc[c] = wfn[c];
            }
        }

        // ---- epilogue for this row-half ----
        #pragma unroll
        for (int mi = 0; mi < 2; ++mi) {
            const int m   = (h * 2 + mi) * 16 + l15;
            const int occ = occ0 + m;
            const long row = 64 * ei[occ] + ti[occ];   // L1/L2-hot
            const int sw  = m & 7;
            #pragma unroll
            for (int c = 0; c < 2; ++c) {
                const int d0 = w * 32 + c * 16 + lk * 4;
                const int cp = (d0 >> 3) ^ sw;
                const int cu = (32 + (d0 >> 3)) ^ sw;
                short4v pv = *(const short4v*)&A_lds[m * 512 + (cp << 3) + (d0 & 7)];
                short4v uv = *(const short4v*)&A_lds[m * 512 + (cu << 3) + (d0 & 7)];
                floatx4 res;
                #pragma unroll
                for (int j = 0; j < 4; ++j) {
                    float fg = sigmoidf(acc[mi][c][j]     + bfv[c][j]);
                    float ag = sigmoidf(acc[mi][c + 2][j] + bav[c][j]);
                    res[j] = fg * bf2f((unsigned short)pv[j])
                           + ag * bf2f((unsigned short)uv[j]);
                }
                *(floatx4*)(out + row * 256 + d0) = res;
            }
        }
    }
}

extern "C" void kernel_launch(void* const* d_in, const int* in_sizes, int n_in,
                              void* d_out, int out_size, void* d_ws, size_t ws_size,
                              hipStream_t stream) {
    const float* flat = (const float*)d_in[0];
    const float* syms = (const float*)d_in[1];
    const float* Wf   = (const float*)d_in[2];
    const float* bf   = (const float*)d_in[3];
    const float* Wa   = (const float*)d_in[4];
    const float* ba   = (const float*)d_in[5];
    const int* ei     = (const int*)d_in[6];
    const int* ti     = (const int*)d_in[7];
    const int* si     = (const int*)d_in[8];
    float* out        = (float*)d_out;

    short* wswz          = (short*)d_ws;                        // 512 KB
    unsigned char* flags = (unsigned char*)d_ws + 512 * 1024;   // 256 KB

    const int n_occ = in_sizes[6];        // 131072
    const int nrows = out_size / 256;     // 262144

    zero_flags_kernel<<<nrows / 1024, 256, 0, stream>>>((unsigned int*)flags);
    mark_kernel<<<(n_occ + 255) / 256, 256, 0, stream>>>(ei, ti, flags, n_occ);
    convert_w_kernel<<<128, 256, 0, stream>>>(Wf, Wa, wswz);

    const int ntiles = n_occ / 64;    // 2048
    const int ncopy  = nrows / 256;   // 1024
    main_kernel<<<ntiles + ncopy, 512, 0, stream>>>(flat, syms, bf, ba,
                                                    ei, ti, si, wswz, flags,
                                                    out, ntiles, ncopy);
}

// Round 8
// 231.772 us; speedup vs baseline: 1.3138x; 1.2847x over previous
//
#include <hip/hip_runtime.h>

typedef __attribute__((ext_vector_type(8))) short short8;
typedef __attribute__((ext_vector_type(4))) short short4v;
typedef __attribute__((ext_vector_type(4))) float floatx4;

__device__ __forceinline__ unsigned short f2bf(float f) {
    unsigned int u = __float_as_uint(f);
    u += 0x7FFFu + ((u >> 16) & 1u);   // round-to-nearest-even
    return (unsigned short)(u >> 16);
}
__device__ __forceinline__ float bf2f(unsigned short s) {
    return __uint_as_float(((unsigned int)s) << 16);
}
__device__ __forceinline__ float sigmoidf(float x) {
    return 1.f / (1.f + __expf(-x));
}

// Wf|Wa fp32 [256,512] -> bf16, MFMA A-operand fragment order.
// short8 index = (g*16 + ks)*64 + lane; lane slot lk*16+l15 holds
// W[d = g*16+l15][k = ks*32+lk*8 .. +8].  g<16 -> Wf, g>=16 -> Wa.
__global__ __launch_bounds__(256)
void convert_w_kernel(const float* __restrict__ Wf,
                      const float* __restrict__ Wa,
                      short* __restrict__ wswz)
{
    int id = blockIdx.x * 256 + threadIdx.x;       // 32768 total
    int slot = id & 63;
    int ks   = (id >> 6) & 15;
    int g    = id >> 10;
    int l15  = slot & 15, lk = slot >> 4;
    const float* base = (g < 16) ? (Wf + (long)(g * 16 + l15) * 512)
                                 : (Wa + (long)((g - 16) * 16 + l15) * 512);
    const float* src = base + ks * 32 + lk * 8;
    floatx4 w0 = *(const floatx4*)src;
    floatx4 w1 = *(const floatx4*)(src + 4);
    short8 o;
    o[0] = (short)f2bf(w0[0]); o[1] = (short)f2bf(w0[1]);
    o[2] = (short)f2bf(w0[2]); o[3] = (short)f2bf(w0[3]);
    o[4] = (short)f2bf(w1[0]); o[5] = (short)f2bf(w1[1]);
    o[6] = (short)f2bf(w1[2]); o[7] = (short)f2bf(w1[3]);
    *(short8*)(wswz + (long)id * 8) = o;
}

__global__ __launch_bounds__(256)
void zero_flags_kernel(unsigned int* __restrict__ flags)   // 256 KB
{
    flags[blockIdx.x * 256 + threadIdx.x] = 0u;
}

__global__ __launch_bounds__(256)
void mark_kernel(const int* __restrict__ ei, const int* __restrict__ ti,
                 unsigned char* __restrict__ flags, int n)
{
    int i = blockIdx.x * 256 + threadIdx.x;
    if (i < n) flags[64 * ei[i] + ti[i]] = 1;
}

// Copy rows NOT updated (one wave per row; wave-uniform flag branch).
__global__ __launch_bounds__(256)
void copy_rest_kernel(const float* __restrict__ flat,
                      const unsigned char* __restrict__ flags,
                      float* __restrict__ out, int nrows)
{
    const int lane = threadIdx.x & 63;
    const int w0   = (blockIdx.x * 256 + threadIdx.x) >> 6;
    const int nw   = (gridDim.x * 256) >> 6;
    for (int row = w0; row < nrows; row += nw) {
        if (flags[row]) continue;
        const floatx4* s = (const floatx4*)(flat + (long)row * 256);
        floatx4*       o = (floatx4*)(out + (long)row * 256);
        o[lane] = s[lane];
    }
}

// Fused gather + bf16 GEMM + gates + combine + FULL-ROW scatter.
// Block: 512 thr (8 waves), 64 occ rows, 64KB LDS (chunk ^= row&7 swizzle).
//   stage:   wave w stages rows w*8..w*8+7 (16-deep gather, conflict-free
//            1KB-contiguous ds_write_b128 per row).
//   MFMA:    Z^T (A=weights from L2 fragment-ordered, B=rows from LDS),
//            acc[4][4]; wave w owns d in [32w,32w+32) for both gates.
//   combine: in-place into A_lds prev-half as bf16 (same slots read),
//            barrier-fenced.
//   store:   wave w writes its 8 rows as contiguous 1KB dwordx4 stores
//            -> full-line writes, NO write-allocate fetch of `out`.
__global__ __launch_bounds__(512, 4)
void gate_kernel(const float* __restrict__ flat,   // [262144,256]
                 const float* __restrict__ syms,   // [20000,256]
                 const float* __restrict__ bfb,
                 const float* __restrict__ bab,
                 const int* __restrict__ ei,
                 const int* __restrict__ ti,
                 const int* __restrict__ si,
                 const short* __restrict__ wswz,
                 float* __restrict__ out)
{
    __shared__ __align__(16) short A_lds[64 * 512];   // 64 KB

    const int tid  = threadIdx.x;
    const int lane = tid & 63;
    const int w    = tid >> 6;     // wave 0..7
    const int occ0 = blockIdx.x * 64;

    // ---- stage: wave w stages rows w*8..w*8+7; lane = 16B chunk ----
    int rowi[8];
    {
        int symi[8];
        #pragma unroll
        for (int i = 0; i < 8; ++i) {
            const int occ = occ0 + w * 8 + i;
            rowi[i] = 64 * ei[occ] + ti[occ];
            symi[i] = si[occ];
        }
        floatx4 va[8], vb[8];
        #pragma unroll
        for (int i = 0; i < 8; ++i) {
            const float* base = (lane < 32)
                ? (flat + (long)rowi[i] * 256 + lane * 8)
                : (syms + (long)symi[i] * 256 + (lane - 32) * 8);
            va[i] = *(const floatx4*)base;
            vb[i] = *(const floatx4*)(base + 4);
        }
        #pragma unroll
        for (int i = 0; i < 8; ++i) {
            short8 o;
            o[0] = (short)f2bf(va[i][0]); o[1] = (short)f2bf(va[i][1]);
            o[2] = (short)f2bf(va[i][2]); o[3] = (short)f2bf(va[i][3]);
            o[4] = (short)f2bf(vb[i][0]); o[5] = (short)f2bf(vb[i][1]);
            o[6] = (short)f2bf(vb[i][2]); o[7] = (short)f2bf(vb[i][3]);
            const int r = w * 8 + i;
            *(short8*)&A_lds[r * 512 + ((lane ^ (r & 7)) << 3)] = o;
        }
    }
    __syncthreads();

    const int l15 = lane & 15;
    const int lk  = lane >> 4;
    const short8* wsv = (const short8*)wswz;

    floatx4 acc[4][4];   // [mi][c: 0,1=forget, 2,3=add]
    #pragma unroll
    for (int mi = 0; mi < 4; ++mi)
        #pragma unroll
        for (int c = 0; c < 4; ++c)
            acc[mi][c] = (floatx4){0.f, 0.f, 0.f, 0.f};

    #pragma unroll
    for (int ks = 0; ks < 16; ++ks) {
        short8 cb[4];
        #pragma unroll
        for (int mi = 0; mi < 4; ++mi) {
            const int m  = mi * 16 + l15;
            const int ch = (ks * 4 + lk) ^ (m & 7);
            cb[mi] = *(const short8*)&A_lds[m * 512 + (ch << 3)];
        }
        #pragma unroll
        for (int c = 0; c < 4; ++c) {
            const int g = (c < 2) ? (w * 2 + c) : (16 + w * 2 + (c - 2));
            const short8 wf = wsv[(g * 16 + ks) * 64 + lane];
            #pragma unroll
            for (int mi = 0; mi < 4; ++mi)
                acc[mi][c] = __builtin_amdgcn_mfma_f32_16x16x32_bf16(
                    wf, cb[mi], acc[mi][c], 0, 0, 0);
        }
    }
    __syncthreads();   // all MFMA reads of A_lds complete

    // ---- combine in-place: lane owns (m, d0..d0+3); result bf16 into
    //      the exact prev-half slots it reads (no cross-lane hazard) ----
    #pragma unroll
    for (int c = 0; c < 2; ++c) {
        const int d0 = w * 32 + c * 16 + lk * 4;
        const floatx4 bfv = *(const floatx4*)(bfb + d0);
        const floatx4 bav = *(const floatx4*)(bab + d0);
        #pragma unroll
        for (int mi = 0; mi < 4; ++mi) {
            const int m  = mi * 16 + l15;
            const int sw = m & 7;
            const int cp = (d0 >> 3) ^ sw;
            const int cu = (32 + (d0 >> 3)) ^ sw;
            const int sub = d0 & 7;
            short4v pv = *(const short4v*)&A_lds[m * 512 + (cp << 3) + sub];
            short4v uv = *(const short4v*)&A_lds[m * 512 + (cu << 3) + sub];
            short4v o;
            #pragma unroll
            for (int j = 0; j < 4; ++j) {
                float fg = sigmoidf(acc[mi][c][j]     + bfv[j]);
                float ag = sigmoidf(acc[mi][c + 2][j] + bav[j]);
                o[j] = (short)f2bf(fg * bf2f((unsigned short)pv[j])
                                 + ag * bf2f((unsigned short)uv[j]));
            }
            *(short4v*)&A_lds[m * 512 + (cp << 3) + sub] = o;
        }
    }
    __syncthreads();   // combined rows ready

    // ---- full-row stores: wave w writes rows w*8..w*8+7, 1KB each ----
    #pragma unroll
    for (int i = 0; i < 8; ++i) {
        const int r = w * 8 + i;
        // lane covers d = lane*4..+3: chunk (lane>>1)^(r&7), half (lane&1)
        short4v s = *(const short4v*)
            &A_lds[r * 512 + (((lane >> 1) ^ (r & 7)) << 3) + (lane & 1) * 4];
        floatx4 o4;
        o4[0] = bf2f((unsigned short)s[0]);
        o4[1] = bf2f((unsigned short)s[1]);
        o4[2] = bf2f((unsigned short)s[2]);
        o4[3] = bf2f((unsigned short)s[3]);
        *(floatx4*)(out + (long)rowi[i] * 256 + lane * 4) = o4;
    }
}

extern "C" void kernel_launch(void* const* d_in, const int* in_sizes, int n_in,
                              void* d_out, int out_size, void* d_ws, size_t ws_size,
                              hipStream_t stream) {
    const float* flat = (const float*)d_in[0];
    const float* syms = (const float*)d_in[1];
    const float* Wf   = (const float*)d_in[2];
    const float* bf   = (const float*)d_in[3];
    const float* Wa   = (const float*)d_in[4];
    const float* ba   = (const float*)d_in[5];
    const int* ei     = (const int*)d_in[6];
    const int* ti     = (const int*)d_in[7];
    const int* si     = (const int*)d_in[8];
    float* out        = (float*)d_out;

    short* wswz          = (short*)d_ws;                        // 512 KB
    unsigned char* flags = (unsigned char*)d_ws + 512 * 1024;   // 256 KB

    const int n_occ = in_sizes[6];        // 131072
    const int nrows = out_size / 256;     // 262144

    zero_flags_kernel<<<nrows / 1024, 256, 0, stream>>>((unsigned int*)flags);
    mark_kernel<<<(n_occ + 255) / 256, 256, 0, stream>>>(ei, ti, flags, n_occ);
    convert_w_kernel<<<128, 256, 0, stream>>>(Wf, Wa, wswz);

    gate_kernel<<<n_occ / 64, 512, 0, stream>>>(flat, syms, bf, ba,
                                                ei, ti, si, wswz, out);

    copy_rest_kernel<<<2048, 256, 0, stream>>>(flat, flags, out, nrows);
}